// Round 1
// 265.475 us; speedup vs baseline: 1.0694x; 1.0694x over previous
//
#include <hip/hip_runtime.h>

// TwoLayerSAGE on MI355X (gfx950). Round 6.
// B=8, N=2048, IN_C=128, HID_C=256, OUT_C=32.
//
// R5 post-mortem: top-5 dispatches are all harness poison fills (78.5us,
// 512MiB each) -> all three kernels < 78.3us; model says floors are
// A-read ~22us + MFMA ~10us. R6 attacks the two modeled inefficiencies:
//   - k_prep A-path: dword -> int4 loads (16B/lane, 1KB/wave-instr), 64x256
//     tiles per wave, 4 ballots/row. 4x fewer VMEM instrs, full-width BW.
//   - xT stored as MFMA-fragment chunks xTt[b][i/32][d][i%32]: every
//     B-fragment load in k_fused1 is one contiguous 1KB wave access instead
//     of 16 divergent 64B probes (row stride was 4KB). Same for hlT ->
//     hlTt[b][i/32][c][i%32] consumed by k_agg2out.
// ws (~16 MB): W1cT | W2cT | deg_inv | bits | xTt | xcat | hlTt | hr

#define B_   8
#define N_   2048
#define INC  128
#define HID  256
#define OUTC 32

typedef __attribute__((ext_vector_type(8))) __bf16 bf16x8;
typedef __attribute__((ext_vector_type(4))) float f32x4;
typedef __attribute__((ext_vector_type(4))) int i32x4;
typedef __attribute__((ext_vector_type(4))) unsigned int u32x4;
typedef __attribute__((ext_vector_type(2))) unsigned int u32x2;

__device__ __forceinline__ unsigned short f2bf(float f) {
  unsigned int u = __float_as_uint(f);
  u += 0x7FFFu + ((u >> 16) & 1u);  // round-to-nearest-even
  return (unsigned short)(u >> 16);
}

__device__ __forceinline__ f32x4 mfma16(bf16x8 a, bf16x8 b, f32x4 c) {
  return __builtin_amdgcn_mfma_f32_16x16x32_bf16(a, b, c, 0, 0, 0);
}

__device__ __forceinline__ bf16x8 ones_frag() {
  union { unsigned short u[8]; bf16x8 v; } o;
#pragma unroll
  for (int i = 0; i < 8; i++) o.u[i] = 0x3F80;
  return o.v;
}

__device__ __forceinline__ void lut_init(u32x2* lut, int t) {
  if (t < 16) {
    unsigned int w0 = (t & 1 ? 0x3F80u : 0u) | (t & 2 ? 0x3F800000u : 0u);
    unsigned int w1 = (t & 4 ? 0x3F80u : 0u) | (t & 8 ? 0x3F800000u : 0u);
    u32x2 e = {w0, w1};
    lut[t] = e;
  }
}

// nibble-LUT expansion: 8 mask bits -> bf16x8 (0.0/1.0)
__device__ __forceinline__ bf16x8 expand8(const u32x2* lut, unsigned int bval) {
  union { u32x2 u2[2]; bf16x8 v; } af;
  af.u2[0] = lut[bval & 15u];
  af.u2[1] = lut[bval >> 4];
  return af.v;
}

// ---------------------------------------------------------------------------
// Fused prep. Blocks (XCD-swizzled: batch = bx & 7 for per-batch sections):
//  [0,512):    A[b][i][j] -> bits[b][j][i/32]; per-wave 64x256 tile, int4
//              loads (16B/lane), 4 ballots/row.
//  [512,768):  x fp32 -> xTt[b][i/32][d][i%32] bf16 AND xcat[b][i][d] bf16
//  [768,832):  W1cT[e][k]: k<128 -> W1_l[k][e], else W1_r[k-128][e]
//  [832,848):  W2cT[n][k]: n<32 -> W2_l[k][n], else W2_r[k][n-32]
__global__ __launch_bounds__(256, 8) void k_prep(
    const int* __restrict__ A, const float* __restrict__ x,
    const float* __restrict__ W1l, const float* __restrict__ W1r,
    const float* __restrict__ W2l, const float* __restrict__ W2r,
    unsigned int* __restrict__ bits, unsigned short* __restrict__ xT,
    unsigned short* __restrict__ xcat,
    unsigned short* __restrict__ W1cT, unsigned short* __restrict__ W2cT) {
  __shared__ unsigned short xls[128 * 72];
  const int bx = blockIdx.x, t = threadIdx.x;
  if (bx < 512) {
    const int w = t >> 6, l = t & 63;
    const int b = bx & 7, tile = bx >> 3;    // XCD swizzle: batch b -> XCD b
    const int gw = tile * 4 + w;             // [0,256): 32 it x 8 jt
    const int it = gw >> 3, jt = gw & 7;
    const int i0 = it * 64, j0 = jt * 256;
    const int* Ap = A + ((size_t)(b * N_) + i0) * N_ + j0 + 4 * l;
    unsigned long long c0 = 0, c1 = 0, c2 = 0, c3 = 0;
#pragma unroll 4
    for (int r = 0; r < 64; r++) {
      i32x4 a = *reinterpret_cast<const i32x4*>(Ap + (size_t)r * N_);
      unsigned long long m0 = __ballot(a[0] != 0);
      unsigned long long m1 = __ballot(a[1] != 0);
      unsigned long long m2 = __ballot(a[2] != 0);
      unsigned long long m3 = __ballot(a[3] != 0);
      c0 |= ((m0 >> l) & 1ull) << r;
      c1 |= ((m1 >> l) & 1ull) << r;
      c2 |= ((m2 >> l) & 1ull) << r;
      c3 |= ((m3 >> l) & 1ull) << r;
    }
    unsigned long long cols[4] = {c0, c1, c2, c3};
#pragma unroll
    for (int c = 0; c < 4; c++)
      *reinterpret_cast<unsigned long long*>(
          bits + ((size_t)(b * N_) + j0 + 4 * l + c) * 64 + (i0 >> 5)) = cols[c];
  } else if (bx < 768) {
    const int bb = bx - 512;
    const int b = bb & 7, it = bb >> 3;      // XCD swizzle
    const int i0 = it * 64;
    const int dq = (t & 31) * 4;
    const int irow = t >> 5;
#pragma unroll
    for (int s = 0; s < 8; s++) {
      int il = s * 8 + irow;
      int i = i0 + il;
      f32x4 v = *reinterpret_cast<const f32x4*>(x + ((size_t)(b * N_ + i)) * INC + dq);
      unsigned int p0 = f2bf(v[0]) | ((unsigned int)f2bf(v[1]) << 16);
      unsigned int p1 = f2bf(v[2]) | ((unsigned int)f2bf(v[3]) << 16);
      u32x2 pk = {p0, p1};
      *reinterpret_cast<u32x2*>(xcat + ((size_t)(b * N_ + i)) * INC + dq) = pk;
      xls[(dq + 0) * 72 + il] = f2bf(v[0]);
      xls[(dq + 1) * 72 + il] = f2bf(v[1]);
      xls[(dq + 2) * 72 + il] = f2bf(v[2]);
      xls[(dq + 3) * 72 + il] = f2bf(v[3]);
    }
    __syncthreads();
    // chunked layout: xTt[((b*64 + ic)*128 + d)*32 + iw], ic = i/32, iw = i%32
    const int d = t >> 1, half = t & 1;
    const u32x4* src = reinterpret_cast<const u32x4*>(&xls[d * 72 + half * 32]);
    u32x4* dst = reinterpret_cast<u32x4*>(
        xT + (((size_t)(b * 64 + it * 2 + half)) * 128 + d) * 32);
#pragma unroll
    for (int q = 0; q < 4; q++) dst[q] = src[q];
  } else if (bx < 832) {
    int base = (bx - 768) * 1024 + t * 4;
#pragma unroll
    for (int q = 0; q < 4; q++) {
      int id = base + q;
      int e = id >> 8, k = id & 255;
      float v = (k < 128) ? W1l[k * 256 + e] : W1r[(k - 128) * 256 + e];
      W1cT[id] = f2bf(v);
    }
  } else {
    int base = (bx - 832) * 1024 + t * 4;
#pragma unroll
    for (int q = 0; q < 4; q++) {
      int id = base + q;
      int n = id >> 8, k = id & 255;
      float v = (n < 32) ? W2l[k * 32 + n] : W2r[k * 32 + (n - 32)];
      W2cT[id] = f2bf(v);
    }
  }
}

// ---------------------------------------------------------------------------
// Fused layer 1: agg (maskT@x, deg in-GEMM, 4-way K-split, 32j x 128d wave
// tile) -> LDS combine -> acat_s[32][264] (agg | x) -> dense1 (relu,@W1) in
// LDS -> hlTt = (h@W2_l)^T bf16 (chunked), hr = h@W2_r + b2 fp32.
// Grid 512 (b = bx&7 -> XCD b, j0 = (bx>>3)*32), 256 thr.
__global__ __launch_bounds__(256, 2) void k_fused1(
    const unsigned int* __restrict__ bits, const unsigned short* __restrict__ xT,
    const unsigned short* __restrict__ xcat,
    const unsigned short* __restrict__ W1cT, const unsigned short* __restrict__ W2cT,
    const float* __restrict__ b1, const float* __restrict__ b2,
    unsigned short* __restrict__ hlT, float* __restrict__ hr,
    float* __restrict__ deg_inv) {
  __shared__ u32x2 lut[16];
  __shared__ __align__(16) float pdeg[4][2][16][4];          // 2 KB
  __shared__ __align__(16) unsigned short acat_s[32 * 264];  // 16.5 KB
  union SU {
    float part[4][6][2][64][4];    // 48 KB: [src_wave][dsi(6 non-owned)][jt][l][r]
    unsigned short hs[32 * 264];   // aliased after combine reads complete
  };
  __shared__ __align__(16) SU su;

  const int t = threadIdx.x;
  const int w = t >> 6, l = t & 63, lr = l & 15, lq = l >> 4;
  lut_init(lut, t);

  const int b = blockIdx.x & 7, j0 = (blockIdx.x >> 3) * 32;

  // early x-part load (cols 128..255 of acat = x in bf16): 32 rows x 128 cols
  const int xr = t >> 3, xs = t & 7;
  const unsigned short* xp = xcat + ((size_t)(b * N_ + j0 + xr)) * INC + xs * 16;
  u32x4 xpart0 = *reinterpret_cast<const u32x4*>(xp);
  u32x4 xpart1 = *reinterpret_cast<const u32x4*>(xp + 8);

  __syncthreads();  // lut ready

  const unsigned int* bp0 = bits + ((size_t)(b * N_ + j0 + lr)) * 64 + w * 16;
  const unsigned int* bp1 = bp0 + (size_t)16 * 64;  // jt=1 -> j += 16
  // chunked xTt: wave w owns K-chunks [w*16, w*16+16)
  const unsigned short* xb = xT + ((size_t)b * 64 + w * 16) * (128 * 32);

  const f32x4 zero = {0.f, 0.f, 0.f, 0.f};
  f32x4 acc[2][8];
#pragma unroll
  for (int jt = 0; jt < 2; jt++)
#pragma unroll
    for (int ds = 0; ds < 8; ds++) acc[jt][ds] = zero;
  f32x4 dacc[2] = {zero, zero};
  const bf16x8 onesf = ones_frag();

  for (int s = 0; s < 16; s++) {
    bf16x8 af0 = expand8(lut, (bp0[s] >> (lq * 8)) & 0xFFu);
    bf16x8 af1 = expand8(lut, (bp1[s] >> (lq * 8)) & 0xFFu);
    dacc[0] = mfma16(af0, onesf, dacc[0]);
    dacc[1] = mfma16(af1, onesf, dacc[1]);
#pragma unroll
    for (int ds = 0; ds < 8; ds++) {
      bf16x8 bfr = *reinterpret_cast<const bf16x8*>(
          xb + (size_t)s * 4096 + (ds * 16 + lr) * 32 + lq * 8);
      acc[0][ds] = mfma16(af0, bfr, acc[0][ds]);
      acc[1][ds] = mfma16(af1, bfr, acc[1][ds]);
    }
  }

  // ---- step 1: dump partials (6 non-owned ds chunks), pdeg, x-part -> LDS
#pragma unroll
  for (int ds = 0; ds < 8; ds++) {
    if ((ds >> 1) != w) {
      int dsi = (ds < 2 * w) ? ds : ds - 2;
#pragma unroll
      for (int jt = 0; jt < 2; jt++)
        *reinterpret_cast<f32x4*>(&su.part[w][dsi][jt][l][0]) = acc[jt][ds];
    }
  }
  if (lr == 0) {
#pragma unroll
    for (int jt = 0; jt < 2; jt++)
      *reinterpret_cast<f32x4*>(&pdeg[w][jt][lq][0]) = dacc[jt];
  }
  *reinterpret_cast<u32x4*>(&acat_s[xr * 264 + 128 + xs * 16]) = xpart0;
  *reinterpret_cast<u32x4*>(&acat_s[xr * 264 + 128 + xs * 16 + 8]) = xpart1;
  __syncthreads();

  // ---- step 3: combine own ds chunks {2w, 2w+1}, scale, write acat_s agg part
  float dinv2[2][4];
#pragma unroll
  for (int jt = 0; jt < 2; jt++)
#pragma unroll
    for (int r = 0; r < 4; r++) {
      float deg = pdeg[0][jt][lq][r] + pdeg[1][jt][lq][r] +
                  pdeg[2][jt][lq][r] + pdeg[3][jt][lq][r];
      dinv2[jt][r] = 1.0f / fmaxf(deg, 1.0f);
    }
  if (w < 2 && lr == 0) {
#pragma unroll
    for (int r = 0; r < 4; r++)
      deg_inv[b * N_ + j0 + w * 16 + lq * 4 + r] = dinv2[w][r];
  }
#pragma unroll
  for (int dd = 0; dd < 2; dd++) {
    int ds = 2 * w + dd;
#pragma unroll
    for (int jt = 0; jt < 2; jt++) {
      f32x4 sum = acc[jt][ds];
#pragma unroll
      for (int src = 0; src < 4; src++) {
        if (src != w) {
          int dsi = (ds < 2 * src) ? ds : ds - 2;
          f32x4 p = *reinterpret_cast<f32x4*>(&su.part[src][dsi][jt][l][0]);
          sum += p;
        }
      }
#pragma unroll
      for (int r = 0; r < 4; r++)
        acat_s[(jt * 16 + lq * 4 + r) * 264 + ds * 16 + lr] =
            f2bf(sum[r] * dinv2[jt][r]);
    }
  }
  __syncthreads();

  // ---- step 5: dense1 from LDS: h = relu(acat_s @ W1cT^T + b1) -> su.hs
  f32x4 acc2[2][4];
#pragma unroll
  for (int jt = 0; jt < 2; jt++)
#pragma unroll
    for (int es = 0; es < 4; es++) acc2[jt][es] = zero;
  const int e0 = w * 64;
#pragma unroll
  for (int ks = 0; ks < 8; ks++) {
    bf16x8 af0 = *reinterpret_cast<const bf16x8*>(&acat_s[lr * 264 + ks * 32 + lq * 8]);
    bf16x8 af1 = *reinterpret_cast<const bf16x8*>(&acat_s[(16 + lr) * 264 + ks * 32 + lq * 8]);
#pragma unroll
    for (int es = 0; es < 4; es++) {
      bf16x8 bfr = *reinterpret_cast<const bf16x8*>(
          W1cT + ((size_t)(e0 + es * 16 + lr)) * HID + ks * 32 + lq * 8);
      acc2[0][es] = mfma16(af0, bfr, acc2[0][es]);
      acc2[1][es] = mfma16(af1, bfr, acc2[1][es]);
    }
  }
  __syncthreads();  // all part reads done; su.hs may now be written
#pragma unroll
  for (int jt = 0; jt < 2; jt++)
#pragma unroll
    for (int es = 0; es < 4; es++) {
      int e = e0 + es * 16 + lr;
      float bias = b1[e];
#pragma unroll
      for (int r = 0; r < 4; r++)
        su.hs[(jt * 16 + lq * 4 + r) * 264 + e] =
            f2bf(fmaxf(acc2[jt][es][r] + bias, 0.0f));
    }
  __syncthreads();

  // ---- step 7: hlTt = (h@W2_l)^T bf16 chunked (waves 0,1); hr = h@W2_r + b2
  const int jt = w & 1, nh = w >> 1;
  f32x4 a2[2] = {zero, zero};
#pragma unroll
  for (int ks = 0; ks < 8; ks++) {
    bf16x8 af = *reinterpret_cast<const bf16x8*>(
        &su.hs[(jt * 16 + lr) * 264 + ks * 32 + lq * 8]);
#pragma unroll
    for (int ns = 0; ns < 2; ns++) {
      bf16x8 bfr = *reinterpret_cast<const bf16x8*>(
          W2cT + ((size_t)(nh * 32 + ns * 16 + lr)) * HID + ks * 32 + lq * 8);
      a2[ns] = mfma16(af, bfr, a2[ns]);
    }
  }
  if (nh == 0) {
#pragma unroll
    for (int ns = 0; ns < 2; ns++) {
      int c = ns * 16 + lr;
      unsigned int p0 = f2bf(a2[ns][0]) | ((unsigned int)f2bf(a2[ns][1]) << 16);
      unsigned int p1 = f2bf(a2[ns][2]) | ((unsigned int)f2bf(a2[ns][3]) << 16);
      u32x2 pk = {p0, p1};
      // hlTt[((b*64 + j/32)*32 + c)*32 + j%32], here j%32 = jt*16 + lq*4 (+r)
      *reinterpret_cast<u32x2*>(
          hlT + (((size_t)(b * 64 + (j0 >> 5))) * 32 + c) * 32 + jt * 16 + lq * 4) = pk;
    }
  } else {
#pragma unroll
    for (int ns = 0; ns < 2; ns++) {
      int c = ns * 16 + lr;
      float bias = b2[c];
#pragma unroll
      for (int r = 0; r < 4; r++)
        hr[((size_t)(b * N_ + j0 + jt * 16 + lq * 4 + r)) * OUTC + c] = a2[ns][r] + bias;
    }
  }
}

// ---------------------------------------------------------------------------
// Fused layer-2 agg + epilogue + log_softmax. Wave tile 32 j x 32 c, 4-way
// K-split, 16 KB LDS combine; waves 0,1 do the epilogue (jt = w).
// Grid 512 (b = bx&7 -> XCD b, j0 = (bx>>3)*32), 256 thr.
__global__ __launch_bounds__(256, 2) void k_agg2out(
    const unsigned int* __restrict__ bits, const unsigned short* __restrict__ hlT,
    const float* __restrict__ deg_inv, const float* __restrict__ hr,
    float* __restrict__ out) {
  __shared__ u32x2 lut[16];
  __shared__ __align__(16) float part[4][2][2][64][4];  // 16 KB
  const int t = threadIdx.x;
  const int w = t >> 6, l = t & 63, lr = l & 15, lq = l >> 4;
  lut_init(lut, t);
  __syncthreads();
  const int b = blockIdx.x & 7, j0 = (blockIdx.x >> 3) * 32;
  const unsigned int* bp0 = bits + ((size_t)(b * N_ + j0 + lr)) * 64 + w * 16;
  const unsigned int* bp1 = bp0 + (size_t)16 * 64;
  // chunked hlTt: wave w owns K-chunks [w*16, w*16+16)
  const unsigned short* hb = hlT + ((size_t)b * 64 + w * 16) * (32 * 32);

  const f32x4 zero = {0.f, 0.f, 0.f, 0.f};
  f32x4 acc[2][2] = {{zero, zero}, {zero, zero}};

  for (int s = 0; s < 16; s++) {
    bf16x8 af0 = expand8(lut, (bp0[s] >> (lq * 8)) & 0xFFu);
    bf16x8 af1 = expand8(lut, (bp1[s] >> (lq * 8)) & 0xFFu);
#pragma unroll
    for (int cs = 0; cs < 2; cs++) {
      bf16x8 bfr = *reinterpret_cast<const bf16x8*>(
          hb + s * 1024 + (cs * 16 + lr) * 32 + lq * 8);
      acc[0][cs] = mfma16(af0, bfr, acc[0][cs]);
      acc[1][cs] = mfma16(af1, bfr, acc[1][cs]);
    }
  }
#pragma unroll
  for (int jt = 0; jt < 2; jt++)
#pragma unroll
    for (int cs = 0; cs < 2; cs++)
      *reinterpret_cast<f32x4*>(&part[w][jt][cs][l][0]) = acc[jt][cs];
  __syncthreads();
  if (w >= 2) return;

  const int jt = w;
  const size_t SZ = (size_t)B_ * N_ * OUTC;
#pragma unroll
  for (int r = 0; r < 4; r++) {
    int j = j0 + jt * 16 + lq * 4 + r;
    float dv = deg_inv[b * N_ + j];
    size_t base = ((size_t)(b * N_ + j)) * OUTC;
    float v0 = (part[0][jt][0][l][r] + part[1][jt][0][l][r] +
                part[2][jt][0][l][r] + part[3][jt][0][l][r]) * dv + hr[base + lr];
    float v1 = (part[0][jt][1][l][r] + part[1][jt][1][l][r] +
                part[2][jt][1][l][r] + part[3][jt][1][l][r]) * dv + hr[base + 16 + lr];
    float m = fmaxf(v0, v1);
#pragma unroll
    for (int d = 1; d < 16; d <<= 1) m = fmaxf(m, __shfl_xor(m, d, 64));
    float s = __expf(v0 - m) + __expf(v1 - m);
#pragma unroll
    for (int d = 1; d < 16; d <<= 1) s += __shfl_xor(s, d, 64);
    float ls = m + __logf(s);
    out[base + lr] = v0 - ls;
    out[base + 16 + lr] = v1 - ls;
    out[SZ + base + lr] = v0;
    out[SZ + base + 16 + lr] = v1;
  }
}

// ---------------------------------------------------------------------------
extern "C" void kernel_launch(void* const* d_in, const int* in_sizes, int n_in,
                              void* d_out, int out_size, void* d_ws, size_t ws_size,
                              hipStream_t stream) {
  (void)in_sizes; (void)n_in; (void)out_size; (void)ws_size;
  const float* x   = (const float*)d_in[0];
  const int*   A   = (const int*)d_in[1];
  const float* W1l = (const float*)d_in[2];
  const float* W1r = (const float*)d_in[3];
  const float* b1  = (const float*)d_in[4];
  const float* W2l = (const float*)d_in[5];
  const float* W2r = (const float*)d_in[6];
  const float* b2  = (const float*)d_in[7];
  float* out = (float*)d_out;

  char* ws = (char*)d_ws;
  unsigned short* W1cT    = (unsigned short*)(ws + 0);         // 131072
  unsigned short* W2cT    = (unsigned short*)(ws + 131072);    // -> 163840
  float*          deg_inv = (float*)(ws + 163840);             // -> 229376
  unsigned int*   bits    = (unsigned int*)(ws + 229376);      // 4 MB -> 4423680
  unsigned short* xTt     = (unsigned short*)(ws + 4423680);   // 4 MB -> 8617984
  unsigned short* xcat    = (unsigned short*)(ws + 8617984);   // 4 MB -> 12812288
  unsigned short* hlTt    = (unsigned short*)(ws + 12812288);  // 1 MB -> 13860864
  float*          hr      = (float*)(ws + 13860864);           // 2 MB -> 15958016

  k_prep   <<<dim3(848),  dim3(256), 0, stream>>>(A, x, W1l, W1r, W2l, W2r,
                                                  bits, xTt, xcat, W1cT, W2cT);
  k_fused1 <<<dim3(512),  dim3(256), 0, stream>>>(bits, xTt, xcat, W1cT, W2cT,
                                                  b1, b2, hlTt, hr, deg_inv);
  k_agg2out<<<dim3(512),  dim3(256), 0, stream>>>(bits, hlTt, deg_inv, hr, out);
}